// Round 1
// baseline (507.804 us; speedup 1.0000x reference)
//
#include <hip/hip_runtime.h>

#define PH 14
#define PW 14
#define CC 512
#define IW 128

// One thread = one (roi, py, px, c4) where c4 is a float4 channel group.
// 128 threads cover the 512 channels of one output pixel.
__global__ __launch_bounds__(256) void roi_pool_kernel(
    const float* __restrict__ img, const int* __restrict__ rois,
    float* __restrict__ out, int npix) {
  long long t = (long long)blockIdx.x * blockDim.x + threadIdx.x;
  int pid = (int)(t >> 7);    // pixel index (roi, py, px)
  int lane = (int)(t & 127);  // float4 group within channels
  if (pid >= npix) return;

  int px = pid % PW;
  int tmp = pid / PW;
  int py = tmp % PH;
  int n = tmp / PH;

  int x0 = rois[n * 4 + 0];
  int y0 = rois[n * 4 + 1];
  int x1 = rois[n * 4 + 2];
  int y1 = rois[n * 4 + 3];
  int in_w = x1 - x0 + 1;
  int in_h = y1 - y0 + 1;

  // Match reference float op order exactly: scale = in/out, then idx*scale.
  float scale_y = (float)in_h / (float)PH;
  float scale_x = (float)in_w / (float)PW;
  float sy = (float)py * scale_y;
  float sx = (float)px * scale_x;
  int yt = (int)floorf(sy);
  int xt = (int)floorf(sx);
  int yb = min(yt + 1, in_h - 1);
  int xr = min(xt + 1, in_w - 1);
  float wy = sy - (float)yt;
  float wx = sx - (float)xt;

  int rt = y0 + yt, rb = y0 + yb;
  int cl = x0 + xt, cr = x0 + xr;

  const float4* imgv = (const float4*)img;
  const int C4 = CC / 4;
  size_t i00 = ((size_t)rt * IW + cl) * C4 + lane;
  size_t i01 = ((size_t)rt * IW + cr) * C4 + lane;
  size_t i10 = ((size_t)rb * IW + cl) * C4 + lane;
  size_t i11 = ((size_t)rb * IW + cr) * C4 + lane;

  float4 v00 = imgv[i00];
  float4 v01 = imgv[i01];
  float4 v10 = imgv[i10];
  float4 v11 = imgv[i11];

  float4 r;
  {
    float top = v00.x + wx * (v01.x - v00.x);
    float bot = v10.x + wx * (v11.x - v10.x);
    r.x = top + wy * (bot - top);
  }
  {
    float top = v00.y + wx * (v01.y - v00.y);
    float bot = v10.y + wx * (v11.y - v10.y);
    r.y = top + wy * (bot - top);
  }
  {
    float top = v00.z + wx * (v01.z - v00.z);
    float bot = v10.z + wx * (v11.z - v10.z);
    r.z = top + wy * (bot - top);
  }
  {
    float top = v00.w + wx * (v01.w - v00.w);
    float bot = v10.w + wx * (v11.w - v10.w);
    r.w = top + wy * (bot - top);
  }

  ((float4*)out)[(size_t)pid * C4 + lane] = r;
}

extern "C" void kernel_launch(void* const* d_in, const int* in_sizes, int n_in,
                              void* d_out, int out_size, void* d_ws, size_t ws_size,
                              hipStream_t stream) {
  const float* img = (const float*)d_in[0];
  const int* rois = (const int*)d_in[1];
  float* out = (float*)d_out;

  int N = in_sizes[1] / 4;          // rois is [N,4]
  int npix = N * PH * PW;           // output pixels
  long long total = (long long)npix * (CC / 4);
  int threads = 256;
  int blocks = (int)((total + threads - 1) / threads);
  roi_pool_kernel<<<blocks, threads, 0, stream>>>(img, rois, out, npix);
}